// Round 3
// baseline (258.981 us; speedup 1.0000x reference)
//
#include <hip/hip_runtime.h>

// Problem constants
#define BI    1152   // B*N = 32*36
#define NREG  36
#define DD    2048
#define RR    512
#define KK    1024   // 2*R
#define ZROWS (BI*NREG)        // 41472
#define MBLK  144              // 4 bi, rows interleaved j*4+g
#define NBLK  256
#define ABUF  (MBLK*32)        // 4608 elems (9 KB) -- A tile per kstep

typedef __bf16 bf16;
typedef __bf16 bf16x8 __attribute__((ext_vector_type(8)));
typedef __bf16 bf16x4 __attribute__((ext_vector_type(4)));
typedef float  f32x4  __attribute__((ext_vector_type(4)));

__device__ __forceinline__ void gl_lds16(const void* g, void* l) {
  __builtin_amdgcn_global_load_lds(
      (const __attribute__((address_space(1))) unsigned int*)g,
      (__attribute__((address_space(3))) unsigned int*)l, 16, 0, 0);
}

// ---------------- fused prep: cvt_mm + transpose_uv + transpose_pt + uvcoord -------
__global__ void k_prep(const float* __restrict__ mm, const float* __restrict__ coords,
                       const float* __restrict__ U_feat, const float* __restrict__ V_feat,
                       const float* __restrict__ P_feat, const float* __restrict__ U_coord,
                       const float* __restrict__ V_coord, const float* __restrict__ P_coord,
                       bf16* __restrict__ mmb, bf16* __restrict__ UT, bf16* __restrict__ VT,
                       bf16* __restrict__ PTt, float* __restrict__ uc, float* __restrict__ vc) {
  __shared__ float tile[32][33];
  int bid = blockIdx.x, tid = threadIdx.x;
  if (bid < 2304) {
    int i = bid * 256 + tid;
    float4 v = ((const float4*)mm)[i];
    bf16x4 o = {(bf16)v.x, (bf16)v.y, (bf16)v.z, (bf16)v.w};
    ((bf16x4*)mmb)[i] = o;
  } else if (bid < 4352) {
    int rel = bid - 2304;
    int zz = rel >> 10, rr = rel & 1023;
    int c0 = (rr & 15) * 32, r0 = (rr >> 4) * 32;     // cols 512, rows 2048
    const float* in = zz ? V_feat : U_feat;
    bf16* outp = zz ? VT : UT;
    int tx = tid & 31, ty = tid >> 5;
#pragma unroll
    for (int k = 0; k < 4; k++)
      tile[ty + 8 * k][tx] = in[(long)(r0 + ty + 8 * k) * 512 + c0 + tx];
    __syncthreads();
#pragma unroll
    for (int k = 0; k < 4; k++)
      outp[(long)(c0 + ty + 8 * k) * 2048 + r0 + tx] = (bf16)tile[tx][ty + 8 * k];
  } else if (bid < 6400) {
    int rel = bid - 4352;
    int zz = rel >> 10, rr = rel & 1023;
    int c0 = (rr & 63) * 32, r0 = (rr >> 6) * 32;     // cols 2048, rows 512
    const float* in = zz ? P_feat : P_coord;
    int koff = zz * 512;
    int tx = tid & 31, ty = tid >> 5;
#pragma unroll
    for (int k = 0; k < 4; k++)
      tile[ty + 8 * k][tx] = in[(long)(r0 + ty + 8 * k) * 2048 + c0 + tx];
    __syncthreads();
    int kc = (koff + r0) >> 5;
#pragma unroll
    for (int k = 0; k < 4; k++) {
      int d = c0 + ty + 8 * k;
      PTt[((long)kc * 2048 + d) * 32 + tx] = (bf16)tile[tx][ty + 8 * k];
    }
  } else {
    int g = bid - 6400;
    float c0 = coords[g * 4 + 0], c1 = coords[g * 4 + 1];
    float c2 = coords[g * 4 + 2], c3 = coords[g * 4 + 3];
#pragma unroll
    for (int i = 0; i < 2; i++) {
      int r = tid + i * 256;
      uc[g * RR + r] = c0 * U_coord[r] + c1 * U_coord[RR + r] + c2 * U_coord[2 * RR + r] + c3 * U_coord[3 * RR + r];
      vc[g * RR + r] = c0 * V_coord[r] + c1 * V_coord[RR + r] + c2 * V_coord[2 * RR + r] + c3 * V_coord[3 * RR + r];
    }
  }
}

// ------- stage 3: uf/vf partials (split-K=2), 64x128 tile, dbuf -------
__launch_bounds__(256)
__global__ void k_gemm_uv(const bf16* __restrict__ mmb, const bf16* __restrict__ UT,
                          const bf16* __restrict__ VT, float* __restrict__ uf,
                          float* __restrict__ vf, float* __restrict__ uf2,
                          float* __restrict__ vf2) {
  __shared__ bf16 lds2[2][6144];   // per buf: A 64x32 (2048) + B 128x32 (4096)
  int uv = blockIdx.z >> 1, kh = blockIdx.z & 1;
  const bf16* Bmat = uv ? VT : UT;
  float* outp = uv ? (kh ? vf2 : vf) : (kh ? uf2 : uf);
  int m0 = blockIdx.x * 64, n0 = blockIdx.y * 128;
  int kbase = kh * 1024;
  int tid = threadIdx.x, wave = tid >> 6, lane = tid & 63;
  int l15 = lane & 15, qv = lane >> 4;
  int qp_c = qv ^ ((l15 >> 1) & 3);
  int qs = (lane & 3) ^ ((lane >> 3) & 3);

  const bf16* gA = mmb + (long)(m0 + wave * 16 + (lane >> 2)) * 2048 + kbase + qs * 8;
  const bf16* gB = Bmat + (long)(n0 + wave * 32 + (lane >> 2)) * 2048 + kbase + qs * 8;
  int lA = wave * 512;
  int lB = 2048 + wave * 1024;

  auto stage = [&](int buf, int k0) {
    bf16* db = &lds2[buf][0];
    gl_lds16(gA + k0, db + lA);
    gl_lds16(gB + k0, db + lB);
    gl_lds16(gB + 16 * 2048 + k0, db + lB + 512);
  };

  f32x4 acc[4][2] = {};
  stage(0, 0);
  for (int k0 = 0; k0 < 1024; k0 += 32) {
    int cur = (k0 >> 5) & 1;
    __syncthreads();
    if (k0 + 32 < 1024) stage(cur ^ 1, k0 + 32);
    bf16x8 a[4], b[2];
#pragma unroll
    for (int mt = 0; mt < 4; mt++)
      a[mt] = *(const bf16x8*)(&lds2[cur][0] + (mt * 16 + l15) * 32 + qp_c * 8);
#pragma unroll
    for (int nt = 0; nt < 2; nt++)
      b[nt] = *(const bf16x8*)(&lds2[cur][2048] + (wave * 32 + nt * 16 + l15) * 32 + qp_c * 8);
#pragma unroll
    for (int mt = 0; mt < 4; mt++)
#pragma unroll
      for (int nt = 0; nt < 2; nt++)
        acc[mt][nt] = __builtin_amdgcn_mfma_f32_16x16x32_bf16(a[mt], b[nt], acc[mt][nt], 0, 0, 0);
  }
#pragma unroll
  for (int mt = 0; mt < 4; mt++)
#pragma unroll
    for (int nt = 0; nt < 2; nt++)
#pragma unroll
      for (int r = 0; r < 4; r++) {
        int row = m0 + mt * 16 + qv * 4 + r;
        int col = n0 + wave * 32 + nt * 16 + l15;
        outp[(long)row * RR + col] = acc[mt][nt][r];
      }
}

// ------- stage 4: z_t[kc][row'][32], row' = (bi>>2)*144 + j*4 + (bi&3) -------
__global__ void k_build_z(const float* __restrict__ uc, const float* __restrict__ vc,
                          const float* __restrict__ uf, const float* __restrict__ vf,
                          const float* __restrict__ uf2, const float* __restrict__ vf2,
                          bf16* __restrict__ z) {
  __shared__ float uL[36 * 128];
  __shared__ float vL[36 * 128];
  int kq = blockIdx.x, b = blockIdx.y, tid = threadIdx.x;
  int kb = (kq & 3) * 128;
  for (int i = tid; i < 1152; i += 256) {
    int row = i >> 5, kk = (i & 31) * 4;
    long src = (long)(b * 36 + row) * RR + kb + kk;
    float4 u4, v4;
    if (kq < 4) {
      u4 = *(const float4*)(uc + src);
      v4 = *(const float4*)(vc + src);
    } else {
      float4 a1 = *(const float4*)(uf + src), a2 = *(const float4*)(uf2 + src);
      float4 b1 = *(const float4*)(vf + src), b2 = *(const float4*)(vf2 + src);
      u4.x = a1.x + a2.x; u4.y = a1.y + a2.y; u4.z = a1.z + a2.z; u4.w = a1.w + a2.w;
      v4.x = b1.x + b2.x; v4.y = b1.y + b2.y; v4.z = b1.z + b2.z; v4.w = b1.w + b2.w;
    }
    *(float4*)&uL[row * 128 + kk] = u4;
    *(float4*)&vL[row * 128 + kk] = v4;
  }
  __syncthreads();
  int cbase = blockIdx.z * 20736;
  for (int c = cbase + tid; c < cbase + 20736; c += 256) {
    int kcl = c / 10368;
    int rem = c - kcl * 10368;
    int row = rem >> 3;             // 0..1295 = gl*36 + j
    int x4 = rem & 7;
    int gl = row / 36;
    int j = row - gl * 36;
    int kl = kcl * 32 + x4 * 4;
    float4 u4 = *(const float4*)&uL[gl * 128 + kl];
    float4 v4 = *(const float4*)&vL[j * 128 + kl];
    float x0 = fmaxf(u4.x * v4.x, 0.f), x1 = fmaxf(u4.y * v4.y, 0.f);
    float x2 = fmaxf(u4.z * v4.z, 0.f), x3 = fmaxf(u4.w * v4.w, 0.f);
    bf16x4 o = {(bf16)x0, (bf16)x1, (bf16)x2, (bf16)x3};
    int bi = b * 36 + gl;
    long rowp = (long)(bi >> 2) * 144 + j * 4 + (bi & 3);
    *(bf16x4*)(z + ((long)(kq * 4 + kcl) * ZROWS + rowp) * 32 + x4 * 4) = o;
  }
}

// ---------------- stage 5: main fused GEMM + register max + residual ----------------
// R11 post-mortem: counted-vmcnt pipeline (R10) was neutral-to-worse -> VMEM latency
// was NOT the stall. Per-slot model: MFMA 1400 cyc (54%), LDS port ~1650 cyc (64%,
// reads 104KB + TA writes 50KB per 2-block slot). B (PTt) has ZERO inter-wave reuse
// (each wave owns a private 64-col strip) -> its LDS round-trip (32KB wr + 32KB rd
// per slot, ~500 cyc of port) is pure waste. R11: load B direct global->VGPR.
// Net fragment mapping (XOR swizzles cancel): lane(l15,qv) holds
// B[d0+wave*64+nt*16+l15][kc*32+qv*8..+7] -> contiguous 4KB/wave global_load_dwordx4.
// B double-buffered in regs (pa/pb, explicit 2-way unroll, static idx per rule #20),
// prefetch distance 1 kstep. LDS keeps only A (4x inter-wave reuse), 3 bufs = 27KB.
// Issue order per iter bottom: stageA(kc+3) then loadB(kc+2) -> steady wait
// vmcnt(aL+4) = 7 (wave0, aL=3) / 6 (waves1-3, aL=2); kc==30 -> 4; kc==31 -> 0.
// VGPR budget: acc 144 + pa/pb 32 + misc ~75 ~= 250 <= 256 (2 blocks/CU preserved).
__launch_bounds__(256, 2)
__global__ void k_main(const bf16* __restrict__ z, const bf16* __restrict__ PTt,
                       const float* __restrict__ mm, float* __restrict__ out) {
  __shared__ bf16 lds[3 * ABUF];   // 27 KB (A only)
  int bid = blockIdx.x;
  int x = bid & 7, t = bid >> 3;
  int dt = t & 7, go = (t >> 3) * 8 + x;   // go 0..287 (4-bi groups)
  int d0 = dt * NBLK;
  int tid = threadIdx.x, wave = tid >> 6, lane = tid & 63;
  int l15 = lane & 15, qv = lane >> 4;
  int qp_c = qv ^ ((l15 >> 1) & 3);
  int qs = (lane & 3) ^ ((lane >> 3) & 3);
  int lroff = (lane >> 2) * 32 + qs * 8;

  const bf16* gA = z + (long)go * ABUF + wave * 1024 + lroff;
  int lA = wave * 1024;
  // direct B: lane reads PTt[kc][d0 + wave*64 + nt*16 + l15][qv*8 .. +7]
  const bf16* gBr = PTt + (long)(d0 + wave * 64 + l15) * 32 + qv * 8;

  auto stageA = [&](int buf) {
    bf16* db = lds + buf * ABUF;
    gl_lds16(gA, db + lA);
    gl_lds16(gA + 512, db + lA + 512);
    if (wave == 0) gl_lds16(gA + 4096, db + 4096);
    gA += (long)ZROWS * 32;
  };

  bf16x8 pa[4], pb[4];
  auto loadB = [&](int kcb, bf16x8 (&p)[4]) {
#pragma unroll
    for (int nt = 0; nt < 4; nt++)
      p[nt] = *(const bf16x8*)(gBr + (long)kcb * 65536 + nt * 512);
  };

  f32x4 acc[9][4] = {};
  // prologue, issue order chosen so steady-state vmcnt counts hold from kc=0:
  // A0, A1, B0, A2, B1  -> younger-than-B0 = A2(aL) + B1(4)
  stageA(0);
  stageA(1);
  loadB(0, pa);
  stageA(2);
  loadB(1, pb);
  int cb = 0;

#define KBODY(KC, PREG)                                                         \
  {                                                                             \
    int kc_ = (KC);                                                             \
    if (kc_ < 30) {                                                             \
      if (wave == 0) asm volatile("s_waitcnt vmcnt(7)" ::: "memory");           \
      else           asm volatile("s_waitcnt vmcnt(6)" ::: "memory");           \
    } else if (kc_ == 30) {                                                     \
      asm volatile("s_waitcnt vmcnt(4)" ::: "memory");                          \
    } else {                                                                    \
      asm volatile("s_waitcnt vmcnt(0)" ::: "memory");                          \
    }                                                                           \
    __builtin_amdgcn_s_barrier();                                               \
    __builtin_amdgcn_sched_barrier(0);                                          \
    const bf16* cur = lds + cb * ABUF;                                          \
    __builtin_amdgcn_s_setprio(1);                                              \
    _Pragma("unroll")                                                           \
    for (int mt = 0; mt < 9; mt++) {                                            \
      bf16x8 av = *(const bf16x8*)(cur + (mt * 16 + l15) * 32 + qp_c * 8);      \
      _Pragma("unroll")                                                         \
      for (int nt = 0; nt < 4; nt++)                                            \
        acc[mt][nt] = __builtin_amdgcn_mfma_f32_16x16x32_bf16(av, PREG[nt],     \
                                                  acc[mt][nt], 0, 0, 0);        \
    }                                                                           \
    __builtin_amdgcn_s_setprio(0);                                              \
    asm volatile("s_waitcnt lgkmcnt(0)" ::: "memory");                          \
    __builtin_amdgcn_sched_barrier(0);                                          \
    __builtin_amdgcn_s_barrier();                                               \
    if (kc_ <= 28) stageA(cb);                                                  \
    if (kc_ <= 29) loadB(kc_ + 2, PREG);                                        \
    cb = (cb == 2) ? 0 : cb + 1;                                                \
  }

  for (int kc = 0; kc < 32; kc += 2) {
    KBODY(kc, pa);
    KBODY(kc + 1, pb);
  }
#undef KBODY

  // epilogue: row-in-block = mt*16 + qv*4 + r = j*4 + g -> g = r, j = mt*4 + qv.
#pragma unroll
  for (int nt = 0; nt < 4; nt++) {
    float mx[4];
#pragma unroll
    for (int r = 0; r < 4; r++) {
      mx[r] = acc[0][nt][r];
#pragma unroll
      for (int mt = 1; mt < 9; mt++) mx[r] = fmaxf(mx[r], acc[mt][nt][r]);
      mx[r] = fmaxf(mx[r], __shfl_xor(mx[r], 16, 64));
      mx[r] = fmaxf(mx[r], __shfl_xor(mx[r], 32, 64));
    }
    if (lane < 16) {
      int col = d0 + wave * 64 + nt * 16 + lane;
#pragma unroll
      for (int r = 0; r < 4; r++) {
        long oa = (long)(go * 4 + r) * DD + col;
        out[oa] = mx[r] + mm[oa];
      }
    }
  }
}

// ---------------- launcher ----------------
extern "C" void kernel_launch(void* const* d_in, const int* in_sizes, int n_in,
                              void* d_out, int out_size, void* d_ws, size_t ws_size,
                              hipStream_t stream) {
  const float* mm     = (const float*)d_in[0];
  const float* coords = (const float*)d_in[1];
  const float* U_feat = (const float*)d_in[2];
  const float* V_feat = (const float*)d_in[3];
  const float* P_feat = (const float*)d_in[4];
  const float* U_coord= (const float*)d_in[5];
  const float* V_coord= (const float*)d_in[6];
  const float* P_coord= (const float*)d_in[7];
  float* out = (float*)d_out;

  char* ws = (char*)d_ws;
  bf16* z   = (bf16*)(ws + 0);                 //  84,934,656 B  [kc][41472 row'][32]
  bf16* PTt = (bf16*)(ws + 84934656);          //   4,194,304 B  [kc][2048][32]
  bf16* mmb = (bf16*)(ws + 89128960);          //   4,718,592 B
  bf16* UT  = (bf16*)(ws + 93847552);          //   2,097,152 B  [512][2048]
  bf16* VT  = (bf16*)(ws + 95944704);          //   2,097,152 B
  float* uf = (float*)(ws + 98041856);         //   2,359,296 B
  float* vf = (float*)(ws + 100401152);
  float* uc = (float*)(ws + 102760448);
  float* vc = (float*)(ws + 105119744);
  float* uf2= (float*)(ws + 107479040);
  float* vf2= (float*)(ws + 109838336);        // end 112,197,632

  k_prep<<<dim3(7552), dim3(256), 0, stream>>>(mm, coords, U_feat, V_feat, P_feat,
                                               U_coord, V_coord, P_coord,
                                               mmb, UT, VT, PTt, uc, vc);
  k_gemm_uv<<<dim3(18, 4, 4), dim3(256), 0, stream>>>(mmb, UT, VT, uf, vf, uf2, vf2);
  k_build_z<<<dim3(8, 32, 2), dim3(256), 0, stream>>>(uc, vc, uf, vf, uf2, vf2, z);
  k_main<<<dim3(2304), dim3(256), 0, stream>>>(z, PTt, mm, out);
}

// Round 4
// 251.968 us; speedup vs baseline: 1.0278x; 1.0278x over previous
//
#include <hip/hip_runtime.h>

// Problem constants
#define BI    1152   // B*N = 32*36
#define NREG  36
#define DD    2048
#define RR    512
#define KK    1024   // 2*R
#define ZROWS (BI*NREG)        // 41472
#define MBLK  144              // 4 bi, rows interleaved j*4+g
#define NBLK  256
#define ABUF  (MBLK*32)        // 4608 elems (9 KB)
#define BBUF  (NBLK*32)        // 8192 elems (16 KB)
#define BUFE  (ABUF+BBUF)      // 12800 elems = 25 KB per buffer

typedef __bf16 bf16;
typedef __bf16 bf16x8 __attribute__((ext_vector_type(8)));
typedef __bf16 bf16x4 __attribute__((ext_vector_type(4)));
typedef float  f32x4  __attribute__((ext_vector_type(4)));

__device__ __forceinline__ void gl_lds16(const void* g, void* l) {
  __builtin_amdgcn_global_load_lds(
      (const __attribute__((address_space(1))) unsigned int*)g,
      (__attribute__((address_space(3))) unsigned int*)l, 16, 0, 0);
}

// ---------------- fused prep: cvt_mm + transpose_uv + transpose_pt + uvcoord -------
__global__ void k_prep(const float* __restrict__ mm, const float* __restrict__ coords,
                       const float* __restrict__ U_feat, const float* __restrict__ V_feat,
                       const float* __restrict__ P_feat, const float* __restrict__ U_coord,
                       const float* __restrict__ V_coord, const float* __restrict__ P_coord,
                       bf16* __restrict__ mmb, bf16* __restrict__ UT, bf16* __restrict__ VT,
                       bf16* __restrict__ PTt, float* __restrict__ uc, float* __restrict__ vc) {
  __shared__ float tile[32][33];
  int bid = blockIdx.x, tid = threadIdx.x;
  if (bid < 2304) {
    int i = bid * 256 + tid;
    float4 v = ((const float4*)mm)[i];
    bf16x4 o = {(bf16)v.x, (bf16)v.y, (bf16)v.z, (bf16)v.w};
    ((bf16x4*)mmb)[i] = o;
  } else if (bid < 4352) {
    int rel = bid - 2304;
    int zz = rel >> 10, rr = rel & 1023;
    int c0 = (rr & 15) * 32, r0 = (rr >> 4) * 32;     // cols 512, rows 2048
    const float* in = zz ? V_feat : U_feat;
    bf16* outp = zz ? VT : UT;
    int tx = tid & 31, ty = tid >> 5;
#pragma unroll
    for (int k = 0; k < 4; k++)
      tile[ty + 8 * k][tx] = in[(long)(r0 + ty + 8 * k) * 512 + c0 + tx];
    __syncthreads();
#pragma unroll
    for (int k = 0; k < 4; k++)
      outp[(long)(c0 + ty + 8 * k) * 2048 + r0 + tx] = (bf16)tile[tx][ty + 8 * k];
  } else if (bid < 6400) {
    int rel = bid - 4352;
    int zz = rel >> 10, rr = rel & 1023;
    int c0 = (rr & 63) * 32, r0 = (rr >> 6) * 32;     // cols 2048, rows 512
    const float* in = zz ? P_feat : P_coord;
    int koff = zz * 512;
    int tx = tid & 31, ty = tid >> 5;
#pragma unroll
    for (int k = 0; k < 4; k++)
      tile[ty + 8 * k][tx] = in[(long)(r0 + ty + 8 * k) * 2048 + c0 + tx];
    __syncthreads();
    int kc = (koff + r0) >> 5;
#pragma unroll
    for (int k = 0; k < 4; k++) {
      int d = c0 + ty + 8 * k;
      PTt[((long)kc * 2048 + d) * 32 + tx] = (bf16)tile[tx][ty + 8 * k];
    }
  } else {
    int g = bid - 6400;
    float c0 = coords[g * 4 + 0], c1 = coords[g * 4 + 1];
    float c2 = coords[g * 4 + 2], c3 = coords[g * 4 + 3];
#pragma unroll
    for (int i = 0; i < 2; i++) {
      int r = tid + i * 256;
      uc[g * RR + r] = c0 * U_coord[r] + c1 * U_coord[RR + r] + c2 * U_coord[2 * RR + r] + c3 * U_coord[3 * RR + r];
      vc[g * RR + r] = c0 * V_coord[r] + c1 * V_coord[RR + r] + c2 * V_coord[2 * RR + r] + c3 * V_coord[3 * RR + r];
    }
  }
}

// ------- stage 3: uf/vf partials (split-K=2), 64x128 tile, dbuf -------
__launch_bounds__(256)
__global__ void k_gemm_uv(const bf16* __restrict__ mmb, const bf16* __restrict__ UT,
                          const bf16* __restrict__ VT, float* __restrict__ uf,
                          float* __restrict__ vf, float* __restrict__ uf2,
                          float* __restrict__ vf2) {
  __shared__ bf16 lds2[2][6144];   // per buf: A 64x32 (2048) + B 128x32 (4096)
  int uv = blockIdx.z >> 1, kh = blockIdx.z & 1;
  const bf16* Bmat = uv ? VT : UT;
  float* outp = uv ? (kh ? vf2 : vf) : (kh ? uf2 : uf);
  int m0 = blockIdx.x * 64, n0 = blockIdx.y * 128;
  int kbase = kh * 1024;
  int tid = threadIdx.x, wave = tid >> 6, lane = tid & 63;
  int l15 = lane & 15, qv = lane >> 4;
  int qp_c = qv ^ ((l15 >> 1) & 3);
  int qs = (lane & 3) ^ ((lane >> 3) & 3);

  const bf16* gA = mmb + (long)(m0 + wave * 16 + (lane >> 2)) * 2048 + kbase + qs * 8;
  const bf16* gB = Bmat + (long)(n0 + wave * 32 + (lane >> 2)) * 2048 + kbase + qs * 8;
  int lA = wave * 512;
  int lB = 2048 + wave * 1024;

  auto stage = [&](int buf, int k0) {
    bf16* db = &lds2[buf][0];
    gl_lds16(gA + k0, db + lA);
    gl_lds16(gB + k0, db + lB);
    gl_lds16(gB + 16 * 2048 + k0, db + lB + 512);
  };

  f32x4 acc[4][2] = {};
  stage(0, 0);
  for (int k0 = 0; k0 < 1024; k0 += 32) {
    int cur = (k0 >> 5) & 1;
    __syncthreads();
    if (k0 + 32 < 1024) stage(cur ^ 1, k0 + 32);
    bf16x8 a[4], b[2];
#pragma unroll
    for (int mt = 0; mt < 4; mt++)
      a[mt] = *(const bf16x8*)(&lds2[cur][0] + (mt * 16 + l15) * 32 + qp_c * 8);
#pragma unroll
    for (int nt = 0; nt < 2; nt++)
      b[nt] = *(const bf16x8*)(&lds2[cur][2048] + (wave * 32 + nt * 16 + l15) * 32 + qp_c * 8);
#pragma unroll
    for (int mt = 0; mt < 4; mt++)
#pragma unroll
      for (int nt = 0; nt < 2; nt++)
        acc[mt][nt] = __builtin_amdgcn_mfma_f32_16x16x32_bf16(a[mt], b[nt], acc[mt][nt], 0, 0, 0);
  }
#pragma unroll
  for (int mt = 0; mt < 4; mt++)
#pragma unroll
    for (int nt = 0; nt < 2; nt++)
#pragma unroll
      for (int r = 0; r < 4; r++) {
        int row = m0 + mt * 16 + qv * 4 + r;
        int col = n0 + wave * 32 + nt * 16 + l15;
        outp[(long)row * RR + col] = acc[mt][nt][r];
      }
}

// ------- stage 4: z_t[kc][row'][32], row' = (bi>>2)*144 + j*4 + (bi&3) -------
// R12: z-split 2 -> 8 (grid (8,32,8)), per-thread loop 81 -> ~20 iters. More blocks
// (512 -> 2048) to cover latency of the scattered 8B stores; work mapping unchanged.
__global__ void k_build_z(const float* __restrict__ uc, const float* __restrict__ vc,
                          const float* __restrict__ uf, const float* __restrict__ vf,
                          const float* __restrict__ uf2, const float* __restrict__ vf2,
                          bf16* __restrict__ z) {
  __shared__ float uL[36 * 128];
  __shared__ float vL[36 * 128];
  int kq = blockIdx.x, b = blockIdx.y, tid = threadIdx.x;
  int kb = (kq & 3) * 128;
  for (int i = tid; i < 1152; i += 256) {
    int row = i >> 5, kk = (i & 31) * 4;
    long src = (long)(b * 36 + row) * RR + kb + kk;
    float4 u4, v4;
    if (kq < 4) {
      u4 = *(const float4*)(uc + src);
      v4 = *(const float4*)(vc + src);
    } else {
      float4 a1 = *(const float4*)(uf + src), a2 = *(const float4*)(uf2 + src);
      float4 b1 = *(const float4*)(vf + src), b2 = *(const float4*)(vf2 + src);
      u4.x = a1.x + a2.x; u4.y = a1.y + a2.y; u4.z = a1.z + a2.z; u4.w = a1.w + a2.w;
      v4.x = b1.x + b2.x; v4.y = b1.y + b2.y; v4.z = b1.z + b2.z; v4.w = b1.w + b2.w;
    }
    *(float4*)&uL[row * 128 + kk] = u4;
    *(float4*)&vL[row * 128 + kk] = v4;
  }
  __syncthreads();
  int cbase = blockIdx.z * 5184;
  for (int c = cbase + tid; c < cbase + 5184; c += 256) {
    int kcl = c / 10368;
    int rem = c - kcl * 10368;
    int row = rem >> 3;             // 0..1295 = gl*36 + j
    int x4 = rem & 7;
    int gl = row / 36;
    int j = row - gl * 36;
    int kl = kcl * 32 + x4 * 4;
    float4 u4 = *(const float4*)&uL[gl * 128 + kl];
    float4 v4 = *(const float4*)&vL[j * 128 + kl];
    float x0 = fmaxf(u4.x * v4.x, 0.f), x1 = fmaxf(u4.y * v4.y, 0.f);
    float x2 = fmaxf(u4.z * v4.z, 0.f), x3 = fmaxf(u4.w * v4.w, 0.f);
    bf16x4 o = {(bf16)x0, (bf16)x1, (bf16)x2, (bf16)x3};
    int bi = b * 36 + gl;
    long rowp = (long)(bi >> 2) * 144 + j * 4 + (bi & 3);
    *(bf16x4*)(z + ((long)(kq * 4 + kcl) * ZROWS + rowp) * 32 + x4 * 4) = o;
  }
}

// ---------------- stage 5: main fused GEMM + register max + residual ----------------
// R12: reverted VERBATIM to the round-0 (R8) version — measured 146.9 us, MfmaUtil 53%,
// conflicts 0. R10 (counted vmcnt + 3-buf + fences) and R11 (B direct-to-reg) were
// both slower (155.5 / 162.9): hand-scheduling fences serialized what the compiler
// already interleaved (guide Common-mistake #5 / m141). This 2-buf __syncthreads
// stage-ahead loop is the proven local optimum for this tile shape.
__launch_bounds__(256, 2)
__global__ void k_main(const bf16* __restrict__ z, const bf16* __restrict__ PTt,
                       const float* __restrict__ mm, float* __restrict__ out) {
  __shared__ bf16 lds[2 * BUFE];   // 50 KB
  int bid = blockIdx.x;
  int x = bid & 7, t = bid >> 3;
  int dt = t & 7, go = (t >> 3) * 8 + x;   // go 0..287 (4-bi groups)
  int d0 = dt * NBLK;
  int tid = threadIdx.x, wave = tid >> 6, lane = tid & 63;
  int l15 = lane & 15, qv = lane >> 4;
  int qp_c = qv ^ ((l15 >> 1) & 3);
  int qs = (lane & 3) ^ ((lane >> 3) & 3);
  int lroff = (lane >> 2) * 32 + qs * 8;

  const bf16* gA = z + (long)go * ABUF + wave * 1024 + lroff;
  const bf16* gB = PTt + (long)d0 * 32 + wave * 2048 + lroff;
  int lA = wave * 1024;
  int lB = ABUF + wave * 2048;

  int sbuf = 0;
  auto stage = [&]() {
    bf16* db = lds + sbuf * BUFE;
    gl_lds16(gA, db + lA);
    gl_lds16(gA + 512, db + lA + 512);
    if (wave == 0) gl_lds16(gA + 4096, db + 4096);
    gl_lds16(gB, db + lB);
    gl_lds16(gB + 512, db + lB + 512);
    gl_lds16(gB + 1024, db + lB + 1024);
    gl_lds16(gB + 1536, db + lB + 1536);
    gA += (long)ZROWS * 32;
    gB += 2048L * 32;
    sbuf ^= 1;
  };

  f32x4 acc[9][4] = {};
  stage();
  for (int kc = 0; kc < 32; kc++) {
    __syncthreads();
    if (kc < 31) stage();
    const bf16* cur = lds + (kc & 1) * BUFE;
    bf16x8 b[4];
#pragma unroll
    for (int nt = 0; nt < 4; nt++)
      b[nt] = *(const bf16x8*)(cur + ABUF + (wave * 64 + nt * 16 + l15) * 32 + qp_c * 8);
#pragma unroll
    for (int mt = 0; mt < 9; mt++) {
      bf16x8 av = *(const bf16x8*)(cur + (mt * 16 + l15) * 32 + qp_c * 8);
#pragma unroll
      for (int nt = 0; nt < 4; nt++)
        acc[mt][nt] = __builtin_amdgcn_mfma_f32_16x16x32_bf16(av, b[nt], acc[mt][nt], 0, 0, 0);
    }
  }

  // epilogue: row-in-block = mt*16 + qv*4 + r = j*4 + g -> g = r, j = mt*4 + qv.
#pragma unroll
  for (int nt = 0; nt < 4; nt++) {
    float mx[4];
#pragma unroll
    for (int r = 0; r < 4; r++) {
      mx[r] = acc[0][nt][r];
#pragma unroll
      for (int mt = 1; mt < 9; mt++) mx[r] = fmaxf(mx[r], acc[mt][nt][r]);
      mx[r] = fmaxf(mx[r], __shfl_xor(mx[r], 16, 64));
      mx[r] = fmaxf(mx[r], __shfl_xor(mx[r], 32, 64));
    }
    if (lane < 16) {
      int col = d0 + wave * 64 + nt * 16 + lane;
#pragma unroll
      for (int r = 0; r < 4; r++) {
        long oa = (long)(go * 4 + r) * DD + col;
        out[oa] = mx[r] + mm[oa];
      }
    }
  }
}

// ---------------- launcher ----------------
extern "C" void kernel_launch(void* const* d_in, const int* in_sizes, int n_in,
                              void* d_out, int out_size, void* d_ws, size_t ws_size,
                              hipStream_t stream) {
  const float* mm     = (const float*)d_in[0];
  const float* coords = (const float*)d_in[1];
  const float* U_feat = (const float*)d_in[2];
  const float* V_feat = (const float*)d_in[3];
  const float* P_feat = (const float*)d_in[4];
  const float* U_coord= (const float*)d_in[5];
  const float* V_coord= (const float*)d_in[6];
  const float* P_coord= (const float*)d_in[7];
  float* out = (float*)d_out;

  char* ws = (char*)d_ws;
  bf16* z   = (bf16*)(ws + 0);                 //  84,934,656 B  [kc][41472 row'][32]
  bf16* PTt = (bf16*)(ws + 84934656);          //   4,194,304 B  [kc][2048][32]
  bf16* mmb = (bf16*)(ws + 89128960);          //   4,718,592 B
  bf16* UT  = (bf16*)(ws + 93847552);          //   2,097,152 B  [512][2048]
  bf16* VT  = (bf16*)(ws + 95944704);          //   2,097,152 B
  float* uf = (float*)(ws + 98041856);         //   2,359,296 B
  float* vf = (float*)(ws + 100401152);
  float* uc = (float*)(ws + 102760448);
  float* vc = (float*)(ws + 105119744);
  float* uf2= (float*)(ws + 107479040);
  float* vf2= (float*)(ws + 109838336);        // end 112,197,632

  k_prep<<<dim3(7552), dim3(256), 0, stream>>>(mm, coords, U_feat, V_feat, P_feat,
                                               U_coord, V_coord, P_coord,
                                               mmb, UT, VT, PTt, uc, vc);
  k_gemm_uv<<<dim3(18, 4, 4), dim3(256), 0, stream>>>(mmb, UT, VT, uf, vf, uf2, vf2);
  k_build_z<<<dim3(8, 32, 8), dim3(256), 0, stream>>>(uc, vc, uf, vf, uf2, vf2, z);
  k_main<<<dim3(2304), dim3(256), 0, stream>>>(z, PTt, mm, out);
}